// Round 2
// baseline (537.813 us; speedup 1.0000x reference)
//
#include <hip/hip_runtime.h>
#include <hip/hip_bf16.h>
#include <cstdint>

// ---------------------------------------------------------------------------
// Gemma4 MoE FFN: dense gated MLP + router + 8 experts (top-2), all GEMMs in
// bf16 MFMA (16x16x32), weights pre-transposed to B^T [N][K] layout.
//
// N=4096 tokens, H=1024, ID=4096, IM=512, E=8, K(top)=2
// ---------------------------------------------------------------------------

typedef __attribute__((ext_vector_type(8))) short short8;
typedef __attribute__((ext_vector_type(4))) float floatx4;
typedef const void __attribute__((address_space(1)))* gptr_t;
typedef void __attribute__((address_space(3)))* sptr_t;

#define BF16 __hip_bfloat16

__device__ __forceinline__ float gelu_tanh(float x) {
  float x3 = x * x * x;
  float t = tanhf(0.7978845608028654f * (x + 0.044715f * x3));
  return 0.5f * x * (1.f + t);
}

// Stage a 128x32 bf16 tile (row-major, row stride = ldg elements) into linear
// LDS [128][32] via global_load_lds width 16. Wave w covers rows w*32..w*32+31.
__device__ __forceinline__ void stage_tile(const BF16* __restrict__ g, BF16* lds,
                                           int ldg, int wave, int lane) {
#pragma unroll
  for (int c = 0; c < 2; ++c) {
    int r = wave * 32 + c * 16 + (lane >> 2);
    const BF16* src = g + (size_t)r * ldg + (lane & 3) * 8;
    BF16* dst = lds + (wave * 32 + c * 16) * 32;  // wave-uniform base; HW adds lane*16B
    __builtin_amdgcn_global_load_lds((gptr_t)src, (sptr_t)dst, 16, 0, 0);
  }
}

// ---------------------------------------------------------------------------
// Fused dual up-GEMM: out[n][j] = gelu(A@Bg)[n][j] * (A@Bu)[n][j] (* combine)
// A [4096][1024] bf16, Bg/Bu = B^T [4096][1024] bf16, out [4096][4096] bf16.
// SCALE_MODE=1: multiply by combine[n][j>>9] (expert path).
// ---------------------------------------------------------------------------
template <int SCALE_MODE>
__launch_bounds__(256, 2)
__global__ void gemm_up(const BF16* __restrict__ A, const BF16* __restrict__ Bg,
                        const BF16* __restrict__ Bu, const float* __restrict__ combine,
                        BF16* __restrict__ out) {
  constexpr int K = 1024, NOUT = 4096;
  __shared__ __align__(16) BF16 lds_a[128 * 32];
  __shared__ __align__(16) BF16 lds_g[128 * 32];
  __shared__ __align__(16) BF16 lds_u[128 * 32];
  const int tid = threadIdx.x, lane = tid & 63, wave = tid >> 6;
  const int wr = wave >> 1, wc = wave & 1;
  const int row0 = blockIdx.y * 128, col0 = blockIdx.x * 128;

  floatx4 accg[4][4] = {};
  floatx4 accu[4][4] = {};

  for (int kt = 0; kt < K / 32; ++kt) {
    stage_tile(A + (size_t)row0 * K + kt * 32, lds_a, K, wave, lane);
    stage_tile(Bg + (size_t)col0 * K + kt * 32, lds_g, K, wave, lane);
    stage_tile(Bu + (size_t)col0 * K + kt * 32, lds_u, K, wave, lane);
    __syncthreads();

    short8 af[4], gf[4], uf[4];
    const int kofs = (lane >> 4) * 8;
#pragma unroll
    for (int mi = 0; mi < 4; ++mi)
      af[mi] = *(const short8*)&lds_a[(wr * 64 + mi * 16 + (lane & 15)) * 32 + kofs];
#pragma unroll
    for (int ni = 0; ni < 4; ++ni) {
      gf[ni] = *(const short8*)&lds_g[(wc * 64 + ni * 16 + (lane & 15)) * 32 + kofs];
      uf[ni] = *(const short8*)&lds_u[(wc * 64 + ni * 16 + (lane & 15)) * 32 + kofs];
    }
#pragma unroll
    for (int mi = 0; mi < 4; ++mi)
#pragma unroll
      for (int ni = 0; ni < 4; ++ni) {
        accg[mi][ni] = __builtin_amdgcn_mfma_f32_16x16x32_bf16(af[mi], gf[ni], accg[mi][ni], 0, 0, 0);
        accu[mi][ni] = __builtin_amdgcn_mfma_f32_16x16x32_bf16(af[mi], uf[ni], accu[mi][ni], 0, 0, 0);
      }
    __syncthreads();
  }

  // Epilogue: C/D layout col=lane&15, row=(lane>>4)*4+j  [m89-verified]
#pragma unroll
  for (int mi = 0; mi < 4; ++mi)
#pragma unroll
    for (int ni = 0; ni < 4; ++ni)
#pragma unroll
      for (int j = 0; j < 4; ++j) {
        int r = row0 + wr * 64 + mi * 16 + (lane >> 4) * 4 + j;
        int c = col0 + wc * 64 + ni * 16 + (lane & 15);
        float h = gelu_tanh(accg[mi][ni][j]) * accu[mi][ni][j];
        if (SCALE_MODE) h *= combine[r * 8 + (c >> 9)];
        out[(size_t)r * NOUT + c] = __float2bfloat16(h);
      }
}

// ---------------------------------------------------------------------------
// Down GEMM: out f32 [4096][1024] = A bf16 [4096][4096] @ B (B^T [1024][4096])
// ---------------------------------------------------------------------------
__launch_bounds__(256, 2)
__global__ void gemm_down(const BF16* __restrict__ A, const BF16* __restrict__ Bt,
                          float* __restrict__ out) {
  constexpr int K = 4096, NOUT = 1024;
  __shared__ __align__(16) BF16 lds_a[128 * 32];
  __shared__ __align__(16) BF16 lds_b[128 * 32];
  const int tid = threadIdx.x, lane = tid & 63, wave = tid >> 6;
  const int wr = wave >> 1, wc = wave & 1;
  const int row0 = blockIdx.y * 128, col0 = blockIdx.x * 128;

  floatx4 acc[4][4] = {};

  for (int kt = 0; kt < K / 32; ++kt) {
    stage_tile(A + (size_t)row0 * K + kt * 32, lds_a, K, wave, lane);
    stage_tile(Bt + (size_t)col0 * K + kt * 32, lds_b, K, wave, lane);
    __syncthreads();

    short8 af[4], bf[4];
    const int kofs = (lane >> 4) * 8;
#pragma unroll
    for (int mi = 0; mi < 4; ++mi)
      af[mi] = *(const short8*)&lds_a[(wr * 64 + mi * 16 + (lane & 15)) * 32 + kofs];
#pragma unroll
    for (int ni = 0; ni < 4; ++ni)
      bf[ni] = *(const short8*)&lds_b[(wc * 64 + ni * 16 + (lane & 15)) * 32 + kofs];
#pragma unroll
    for (int mi = 0; mi < 4; ++mi)
#pragma unroll
      for (int ni = 0; ni < 4; ++ni)
        acc[mi][ni] = __builtin_amdgcn_mfma_f32_16x16x32_bf16(af[mi], bf[ni], acc[mi][ni], 0, 0, 0);
    __syncthreads();
  }

#pragma unroll
  for (int mi = 0; mi < 4; ++mi)
#pragma unroll
    for (int ni = 0; ni < 4; ++ni)
#pragma unroll
      for (int j = 0; j < 4; ++j) {
        int r = row0 + wr * 64 + mi * 16 + (lane >> 4) * 4 + j;
        int c = col0 + wc * 64 + ni * 16 + (lane & 15);
        out[(size_t)r * NOUT + c] = acc[mi][ni][j];
      }
}

// ---------------------------------------------------------------------------
// Router: per token — rmsnorm stats, xr (w_pre2, bf16), router logits,
// softmax, top-2, combine[N][8].  One wave per token, 4 tokens per block.
// ---------------------------------------------------------------------------
__global__ void router_kernel(const float* __restrict__ residual,
                              const float* __restrict__ w_pre2,
                              const float* __restrict__ router_scale,
                              const float* __restrict__ per_expert_scale,
                              const float* __restrict__ Wr,  // [1024][8]
                              BF16* __restrict__ xr,         // [4096][1024]
                              float* __restrict__ combine) { // [4096][8]
  const int lane = threadIdx.x & 63, wave = threadIdx.x >> 6;
  const int n = blockIdx.x * 4 + wave;
  const float* res = residual + (size_t)n * 1024;

  float v[16];
  float ss = 0.f;
#pragma unroll
  for (int i = 0; i < 16; ++i) {
    v[i] = res[lane + i * 64];
    ss += v[i] * v[i];
  }
#pragma unroll
  for (int off = 32; off; off >>= 1) ss += __shfl_xor(ss, off);
  const float inv = rsqrtf(ss * (1.f / 1024.f) + 1e-6f);

  float logits[8] = {};
#pragma unroll
  for (int i = 0; i < 16; ++i) {
    int h = lane + i * 64;
    float nv = v[i] * inv;
    xr[(size_t)n * 1024 + h] = __float2bfloat16(nv * w_pre2[h]);
    float yv = nv * router_scale[h];
#pragma unroll
    for (int e = 0; e < 8; ++e) logits[e] += yv * Wr[h * 8 + e];
  }
#pragma unroll
  for (int e = 0; e < 8; ++e)
#pragma unroll
    for (int off = 32; off; off >>= 1) logits[e] += __shfl_xor(logits[e], off);

  if (lane == 0) {
    const float hscale = 0.03125f;  // 1024^-0.5
    float mx = -1e30f;
#pragma unroll
    for (int e = 0; e < 8; ++e) {
      logits[e] *= hscale;
      mx = fmaxf(mx, logits[e]);
    }
    float p[8];
#pragma unroll
    for (int e = 0; e < 8; ++e) p[e] = __expf(logits[e] - mx);
    // top-2 (lowest index wins ties, matching lax.top_k)
    int i0 = 0;
#pragma unroll
    for (int e = 1; e < 8; ++e)
      if (p[e] > p[i0]) i0 = e;
    int i1 = -1;
#pragma unroll
    for (int e = 0; e < 8; ++e)
      if (e != i0 && (i1 < 0 || p[e] > p[i1])) i1 = e;
    float w0 = p[i0], w1 = p[i1];
    float swv = w0 + w1;
    w0 = w0 / swv * per_expert_scale[i0];
    w1 = w1 / swv * per_expert_scale[i1];
#pragma unroll
    for (int e = 0; e < 8; ++e) combine[n * 8 + e] = 0.f;
    combine[n * 8 + i0] = w0;
    combine[n * 8 + i1] = w1;
  }
}

// ---------------------------------------------------------------------------
// Finalize: out[n][h] = rmsnorm(dense)[h]*w1[h] + rmsnorm(routed)[h]*w2[h]
// ---------------------------------------------------------------------------
__global__ void finalize_kernel(const float* __restrict__ dp, const float* __restrict__ rp,
                                const float* __restrict__ w1, const float* __restrict__ w2,
                                float* __restrict__ out) {
  const int n = blockIdx.x, t = threadIdx.x;
  float d[4], r[4];
  float ssd = 0.f, ssr = 0.f;
#pragma unroll
  for (int i = 0; i < 4; ++i) {
    int h = t + i * 256;
    d[i] = dp[(size_t)n * 1024 + h];
    r[i] = rp[(size_t)n * 1024 + h];
    ssd += d[i] * d[i];
    ssr += r[i] * r[i];
  }
#pragma unroll
  for (int off = 32; off; off >>= 1) {
    ssd += __shfl_xor(ssd, off);
    ssr += __shfl_xor(ssr, off);
  }
  __shared__ float sd[4], sr[4];
  int wave = t >> 6, lane = t & 63;
  if (lane == 0) { sd[wave] = ssd; sr[wave] = ssr; }
  __syncthreads();
  ssd = sd[0] + sd[1] + sd[2] + sd[3];
  ssr = sr[0] + sr[1] + sr[2] + sr[3];
  const float invd = rsqrtf(ssd * (1.f / 1024.f) + 1e-6f);
  const float invr = rsqrtf(ssr * (1.f / 1024.f) + 1e-6f);
#pragma unroll
  for (int i = 0; i < 4; ++i) {
    int h = t + i * 256;
    out[(size_t)n * 1024 + h] = d[i] * invd * w1[h] + r[i] * invr * w2[h];
  }
}

// ---------------------------------------------------------------------------
// f32 -> bf16 transpose (batched): out[b][c][r] = bf16(in[b][r][c])
// block (32,8), grid (cols/32, rows/32, batch)
// ---------------------------------------------------------------------------
__global__ void transpose_cvt(const float* __restrict__ in, BF16* __restrict__ out,
                              int rows, int cols) {
  __shared__ float tile[32][33];
  const size_t boff = (size_t)blockIdx.z * rows * cols;
  in += boff;
  out += boff;
  const int c0 = blockIdx.x * 32, r0 = blockIdx.y * 32;
#pragma unroll
  for (int i = 0; i < 4; ++i)
    tile[threadIdx.y + i * 8][threadIdx.x] =
        in[(size_t)(r0 + threadIdx.y + i * 8) * cols + c0 + threadIdx.x];
  __syncthreads();
#pragma unroll
  for (int i = 0; i < 4; ++i)
    out[(size_t)(c0 + threadIdx.y + i * 8) * rows + r0 + threadIdx.x] =
        __float2bfloat16(tile[threadIdx.x][threadIdx.y + i * 8]);
}

// f32 -> bf16 elementwise, 4 elems/thread, exact grid
__global__ void cvt_bf16_kernel(const float* __restrict__ in, BF16* __restrict__ out) {
  const size_t i = ((size_t)blockIdx.x * blockDim.x + threadIdx.x) * 4;
  float4 v = *(const float4*)(in + i);
  BF16 o[4] = {__float2bfloat16(v.x), __float2bfloat16(v.y),
               __float2bfloat16(v.z), __float2bfloat16(v.w)};
  *(uint2*)(out + i) = *(const uint2*)o;
}

// ---------------------------------------------------------------------------
extern "C" void kernel_launch(void* const* d_in, const int* in_sizes, int n_in,
                              void* d_out, int out_size, void* d_ws, size_t ws_size,
                              hipStream_t stream) {
  const float* x = (const float*)d_in[0];
  const float* res = (const float*)d_in[1];
  const float* Wg_d = (const float*)d_in[2];
  const float* Wu_d = (const float*)d_in[3];
  const float* Wd_d = (const float*)d_in[4];
  const float* w_post1 = (const float*)d_in[5];
  const float* w_pre2 = (const float*)d_in[6];
  const float* w_post2 = (const float*)d_in[7];
  const float* router_scale = (const float*)d_in[8];
  const float* per_expert_scale = (const float*)d_in[9];
  const float* Wr = (const float*)d_in[10];
  const float* Wg_e = (const float*)d_in[11];
  const float* Wu_e = (const float*)d_in[12];
  const float* Wd_e = (const float*)d_in[13];
  float* out = (float*)d_out;

  char* ws = (char*)d_ws;
  const size_t MB = 1ull << 20;
  BF16* x_b = (BF16*)(ws + 0 * MB);      // [4096][1024]
  BF16* xr_b = (BF16*)(ws + 8 * MB);     // [4096][1024]
  BF16* WgdT = (BF16*)(ws + 16 * MB);    // [4096][1024]
  BF16* WudT = (BF16*)(ws + 24 * MB);    // [4096][1024]
  BF16* WddT = (BF16*)(ws + 32 * MB);    // [1024][4096]
  BF16* WgeT = (BF16*)(ws + 40 * MB);    // [8][512][1024] flat [4096][1024]
  BF16* WueT = (BF16*)(ws + 48 * MB);    // same
  BF16* WdeT = (BF16*)(ws + 56 * MB);    // [1024][4096]
  BF16* HBUF = (BF16*)(ws + 64 * MB);    // [4096][4096] (H1 then Gall)
  float* dense_pre = (float*)(ws + 96 * MB);   // [4096][1024]
  float* routed_pre = (float*)(ws + 112 * MB); // [4096][1024]
  float* combine = (float*)(ws + 128 * MB);    // [4096][8]

  dim3 tb(32, 8);
  // pre-pass: conversions + weight transposes (B^T layout, bf16)
  cvt_bf16_kernel<<<4096, 256, 0, stream>>>(x, x_b);
  transpose_cvt<<<dim3(4096 / 32, 1024 / 32, 1), tb, 0, stream>>>(Wg_d, WgdT, 1024, 4096);
  transpose_cvt<<<dim3(4096 / 32, 1024 / 32, 1), tb, 0, stream>>>(Wu_d, WudT, 1024, 4096);
  transpose_cvt<<<dim3(1024 / 32, 4096 / 32, 1), tb, 0, stream>>>(Wd_d, WddT, 4096, 1024);
  transpose_cvt<<<dim3(512 / 32, 1024 / 32, 8), tb, 0, stream>>>(Wg_e, WgeT, 1024, 512);
  transpose_cvt<<<dim3(512 / 32, 1024 / 32, 8), tb, 0, stream>>>(Wu_e, WueT, 1024, 512);
  transpose_cvt<<<dim3(1024 / 32, 4096 / 32, 1), tb, 0, stream>>>(Wd_e, WdeT, 4096, 1024);

  // router: xr (bf16) + combine
  router_kernel<<<1024, 256, 0, stream>>>(res, w_pre2, router_scale, per_expert_scale,
                                          Wr, xr_b, combine);

  // dense path
  gemm_up<0><<<dim3(32, 32), 256, 0, stream>>>(x_b, WgdT, WudT, nullptr, HBUF);
  gemm_down<<<dim3(8, 32), 256, 0, stream>>>(HBUF, WddT, dense_pre);

  // expert path (combine folded into hidden activations; reuse HBUF)
  gemm_up<1><<<dim3(32, 32), 256, 0, stream>>>(xr_b, WgeT, WueT, combine, HBUF);
  gemm_down<<<dim3(8, 32), 256, 0, stream>>>(HBUF, WdeT, routed_pre);

  // out = rmsnorm(dense)*w_post1 + rmsnorm(routed)*w_post2
  finalize_kernel<<<4096, 256, 0, stream>>>(dense_pre, routed_pre, w_post1, w_post2, out);
}